// Round 1
// baseline (3113.986 us; speedup 1.0000x reference)
//
#include <hip/hip_runtime.h>

#define N_PTS   16384
#define M_CENT  1024
#define K_SMP   32
#define C_FEAT  64
#define C_IN    67

// ---------------------------------------------------------------------------
// 64-bit xor shuffle built from two 32-bit shuffles (guaranteed available)
__device__ inline unsigned long long shfl_xor_u64(unsigned long long v, int m) {
    int lo = (int)(unsigned int)v;
    int hi = (int)(unsigned int)(v >> 32);
    lo = __shfl_xor(lo, m);
    hi = __shfl_xor(hi, m);
    return ((unsigned long long)(unsigned int)hi << 32) | (unsigned int)lo;
}

// ---------------------------------------------------------------------------
// FPS: one block per batch, 1024 threads, 16 points/lane held in registers.
// Must match numpy f32 semantics bit-exactly: no FMA contraction,
// sum order (dx^2+dy^2)+dz^2, argmax first-index-wins.
__global__ __launch_bounds__(1024) void fps_kernel(
    const float* __restrict__ xyz,   // (B,N,3)
    float* __restrict__ newxyz_out,  // (B,M,3)   d_out region 0
    float* __restrict__ idxf_out)    // (B,M)     d_out region 2 (float-encoded)
{
#pragma clang fp contract(off)
    const int b   = blockIdx.x;
    const int tid = threadIdx.x;
    const float* P = xyz + (size_t)b * N_PTS * 3;

    float px[16], py[16], pz[16], mind[16];
#pragma unroll
    for (int i = 0; i < 16; ++i) {
        const int p = tid + (i << 10);
        px[i] = P[p * 3 + 0];
        py[i] = P[p * 3 + 1];
        pz[i] = P[p * 3 + 2];
        mind[i] = __int_as_float(0x7f800000);  // +inf
    }

    __shared__ float cs[3];
    __shared__ unsigned long long part[16];

    if (tid == 0) {
        cs[0] = P[0]; cs[1] = P[1]; cs[2] = P[2];
        idxf_out[b * M_CENT] = 0.0f;
        newxyz_out[(b * M_CENT) * 3 + 0] = P[0];
        newxyz_out[(b * M_CENT) * 3 + 1] = P[1];
        newxyz_out[(b * M_CENT) * 3 + 2] = P[2];
    }
    __syncthreads();

    for (int j = 1; j < M_CENT; ++j) {
        const float cx = cs[0], cy = cs[1], cz = cs[2];
        float bv = -1.0f;
        int   bi = 0;
#pragma unroll
        for (int i = 0; i < 16; ++i) {
            float dx = px[i] - cx;
            float dy = py[i] - cy;
            float dz = pz[i] - cz;
            float xx = dx * dx;
            float yy = dy * dy;
            float zz = dz * dz;
            float d  = (xx + yy) + zz;          // numpy order, no fma
            float mn = fminf(mind[i], d);
            mind[i] = mn;
            if (mn > bv) { bv = mn; bi = i; }   // strict > keeps earliest
        }
        const int bidx = tid + (bi << 10);
        // pack: value bits (monotonic for >=0) high, inverted index low -> ties pick smaller idx
        unsigned long long key =
            ((unsigned long long)__float_as_uint(bv) << 32) |
            (unsigned long long)(unsigned int)(16383 - bidx);

#pragma unroll
        for (int off = 32; off >= 1; off >>= 1) {
            unsigned long long o = shfl_xor_u64(key, off);
            if (o > key) key = o;
        }
        if ((tid & 63) == 0) part[tid >> 6] = key;
        __syncthreads();

        unsigned long long k2 = part[tid & 15];
#pragma unroll
        for (int off = 8; off >= 1; off >>= 1) {
            unsigned long long o = shfl_xor_u64(k2, off);
            if (o > k2) k2 = o;
        }
        const int widx = 16383 - (int)(k2 & 0xFFFFFFFFull);

        if (tid == (widx & 1023)) {              // owner thread of winning point
            const int ii = widx >> 10;
            float wx = 0.f, wy = 0.f, wz = 0.f;
#pragma unroll
            for (int i = 0; i < 16; ++i)
                if (i == ii) { wx = px[i]; wy = py[i]; wz = pz[i]; }
            cs[0] = wx; cs[1] = wy; cs[2] = wz;
            idxf_out[b * M_CENT + j] = (float)widx;
            newxyz_out[(b * M_CENT + j) * 3 + 0] = wx;
            newxyz_out[(b * M_CENT + j) * 3 + 1] = wy;
            newxyz_out[(b * M_CENT + j) * 3 + 2] = wz;
        }
        __syncthreads();
    }
}

// ---------------------------------------------------------------------------
// Ball query: one wave per centroid, ballot-based first-32-in-ball scan.
__global__ __launch_bounds__(256) void ball_kernel(
    const float* __restrict__ xyz,
    const float* __restrict__ newxyz,   // read back from d_out region 0
    int* __restrict__ nidx)             // (B,M,K) in ws
{
#pragma clang fp contract(off)
    const float R2 = (float)(0.1 * 0.1);   // matches f32(0.01) = 0x3C23D70A
    const int gw   = blockIdx.x * 4 + (threadIdx.x >> 6);
    const int lane = threadIdx.x & 63;
    const int b    = gw >> 10;
    const float* P = xyz + (size_t)b * N_PTS * 3;
    const float cx = newxyz[gw * 3 + 0];
    const float cy = newxyz[gw * 3 + 1];
    const float cz = newxyz[gw * 3 + 2];
    int* out = nidx + gw * K_SMP;

    int cnt = 0, first = -1;
    for (int base = 0; base < N_PTS; base += 64) {
        const int n = base + lane;
        float dx = P[n * 3 + 0] - cx;
        float dy = P[n * 3 + 1] - cy;
        float dz = P[n * 3 + 2] - cz;
        float xx = dx * dx, yy = dy * dy, zz = dz * dz;
        float d2 = (xx + yy) + zz;
        bool inb = d2 < R2;
        unsigned long long mask = __ballot(inb);
        if (mask) {
            if (first < 0) first = base + __ffsll(mask) - 1;
            int before = __popcll(mask & ((1ull << lane) - 1ull));
            int slot = cnt + before;
            if (inb && slot < K_SMP) out[slot] = n;
            cnt += __popcll(mask);
            if (cnt >= K_SMP) break;
        }
    }
    // pad remaining slots with first in-ball index (always exists: centroid itself)
    for (int s = cnt + lane; s < K_SMP; s += 64) out[s] = first;
}

// ---------------------------------------------------------------------------
// Weight transpose: W (OC,IC) row-major -> WT (IC,OC) row-major
__global__ void transpose_w(const float* __restrict__ src, float* __restrict__ dst,
                            int OC, int IC)
{
    int i = blockIdx.x * 256 + threadIdx.x;
    if (i < OC * IC) {
        int oc = i / IC, ic = i - oc * IC;
        dst[ic * OC + oc] = src[i];
    }
}

// ---------------------------------------------------------------------------
// Fused gather + 5 conv1x1 layers + residuals + maxpool.
// One block = 2 centroids = 64 columns. 256 threads: tx(0..15) -> 4 cols,
// ty(0..15) -> 8 rows. Activations staged in LDS; weights (pre-transposed)
// read from global (L2-resident).
__global__ __launch_bounds__(256) void mlp_kernel(
    const float* __restrict__ xyz, const float* __restrict__ feat,
    const float* __restrict__ newxyz, const int* __restrict__ nidx,
    const float* __restrict__ WaT, const float* __restrict__ ba,
    const float* __restrict__ WbT, const float* __restrict__ bb,
    const float* __restrict__ WsT, const float* __restrict__ bs,
    const float* __restrict__ WcT, const float* __restrict__ bc,
    const float* __restrict__ WdT, const float* __restrict__ bd,
    float* __restrict__ pooled)   // (B,128,M)  d_out region 1
{
    __shared__ __align__(16) float Xs[C_IN][68];
    __shared__ __align__(16) float Hs[128][68];
    __shared__ __align__(16) float Ts[64][68];

    const int tid  = threadIdx.x;
    const int tx   = tid & 15;
    const int ty   = tid >> 4;
    const int c0   = tx * 4;
    const int r0   = ty * 8;
    const int cen0 = blockIdx.x * 2;

    // ---- gather g = [rel_xyz(3); features(64)] into Xs ----
    {
        const int c  = tid & 63;
        const int ci = cen0 + (c >> 5);
        const int b  = ci >> 10;
        const int nn = nidx[ci * K_SMP + (c & 31)];
        const float* P = xyz + (size_t)b * N_PTS * 3;
        const float* F = feat + (size_t)b * C_FEAT * N_PTS;
#pragma unroll 1
        for (int rr = (tid >> 6); rr < C_IN; rr += 4) {
            float v;
            if (rr < 3) v = P[nn * 3 + rr] - newxyz[ci * 3 + rr];
            else        v = F[(rr - 3) * N_PTS + nn];
            Xs[rr][c] = v;
        }
    }
    __syncthreads();

    // ---- layers A (h1 = relu(Wa@g+ba)) and S (s = Ws@g+bs), both read Xs ----
    float accA[8][4], accS[8][4];
#pragma unroll
    for (int i = 0; i < 8; ++i)
#pragma unroll
        for (int j = 0; j < 4; ++j) { accA[i][j] = 0.f; accS[i][j] = 0.f; }

    for (int ic = 0; ic < C_IN; ++ic) {
        const float4 xv = *(const float4*)&Xs[ic][c0];
        const float4 a0 = *(const float4*)(WaT + ic * 128 + r0);
        const float4 a1 = *(const float4*)(WaT + ic * 128 + r0 + 4);
        const float4 s0 = *(const float4*)(WsT + ic * 128 + r0);
        const float4 s1 = *(const float4*)(WsT + ic * 128 + r0 + 4);
        const float wa[8] = {a0.x,a0.y,a0.z,a0.w,a1.x,a1.y,a1.z,a1.w};
        const float ws2[8] = {s0.x,s0.y,s0.z,s0.w,s1.x,s1.y,s1.z,s1.w};
        const float xs[4] = {xv.x, xv.y, xv.z, xv.w};
#pragma unroll
        for (int i = 0; i < 8; ++i)
#pragma unroll
            for (int j = 0; j < 4; ++j) {
                accA[i][j] = fmaf(wa[i],  xs[j], accA[i][j]);
                accS[i][j] = fmaf(ws2[i], xs[j], accS[i][j]);
            }
    }

    {   // h1 -> Hs
        const float4 b0 = *(const float4*)(ba + r0);
        const float4 b1 = *(const float4*)(ba + r0 + 4);
        const float bav[8] = {b0.x,b0.y,b0.z,b0.w,b1.x,b1.y,b1.z,b1.w};
#pragma unroll
        for (int i = 0; i < 8; ++i) {
            float4 hv;
            hv.x = fmaxf(accA[i][0] + bav[i], 0.f);
            hv.y = fmaxf(accA[i][1] + bav[i], 0.f);
            hv.z = fmaxf(accA[i][2] + bav[i], 0.f);
            hv.w = fmaxf(accA[i][3] + bav[i], 0.f);
            *(float4*)&Hs[r0 + i][c0] = hv;
        }
    }
    __syncthreads();

    // ---- layer B: h2 = Wb@h1 + bb ; h = relu(h2 + s) ----
    float accB[8][4];
#pragma unroll
    for (int i = 0; i < 8; ++i)
#pragma unroll
        for (int j = 0; j < 4; ++j) accB[i][j] = 0.f;

    for (int ic = 0; ic < 128; ++ic) {
        const float4 xv = *(const float4*)&Hs[ic][c0];
        const float4 w0 = *(const float4*)(WbT + ic * 128 + r0);
        const float4 w1 = *(const float4*)(WbT + ic * 128 + r0 + 4);
        const float wb[8] = {w0.x,w0.y,w0.z,w0.w,w1.x,w1.y,w1.z,w1.w};
        const float xs[4] = {xv.x, xv.y, xv.z, xv.w};
#pragma unroll
        for (int i = 0; i < 8; ++i)
#pragma unroll
            for (int j = 0; j < 4; ++j)
                accB[i][j] = fmaf(wb[i], xs[j], accB[i][j]);
    }

    float hreg[8][4];
    {
        const float4 p0 = *(const float4*)(bb + r0);
        const float4 p1 = *(const float4*)(bb + r0 + 4);
        const float4 q0 = *(const float4*)(bs + r0);
        const float4 q1 = *(const float4*)(bs + r0 + 4);
        const float bbv[8] = {p0.x,p0.y,p0.z,p0.w,p1.x,p1.y,p1.z,p1.w};
        const float bsv[8] = {q0.x,q0.y,q0.z,q0.w,q1.x,q1.y,q1.z,q1.w};
#pragma unroll
        for (int i = 0; i < 8; ++i)
#pragma unroll
            for (int j = 0; j < 4; ++j)
                hreg[i][j] = fmaxf((accB[i][j] + bbv[i]) + (accS[i][j] + bsv[i]), 0.f);
    }
    __syncthreads();          // everyone done reading h1
#pragma unroll
    for (int i = 0; i < 8; ++i) {
        float4 hv = {hreg[i][0], hreg[i][1], hreg[i][2], hreg[i][3]};
        *(float4*)&Hs[r0 + i][c0] = hv;   // Hs now holds h
    }
    __syncthreads();

    // ---- layers C (512 rows, 8 chunks of 64) and D (accumulated) ----
    float inv[8][4];
#pragma unroll
    for (int i = 0; i < 8; ++i)
#pragma unroll
        for (int j = 0; j < 4; ++j) inv[i][j] = 0.f;

    for (int cc = 0; cc < 8; ++cc) {
        float accC[4][4];
#pragma unroll
        for (int i = 0; i < 4; ++i)
#pragma unroll
            for (int j = 0; j < 4; ++j) accC[i][j] = 0.f;

        const int rc = cc * 64 + ty * 4;
        for (int ic = 0; ic < 128; ++ic) {
            const float4 xv = *(const float4*)&Hs[ic][c0];
            const float4 w  = *(const float4*)(WcT + ic * 512 + rc);
            const float wc4[4] = {w.x, w.y, w.z, w.w};
            const float xs[4]  = {xv.x, xv.y, xv.z, xv.w};
#pragma unroll
            for (int i = 0; i < 4; ++i)
#pragma unroll
                for (int j = 0; j < 4; ++j)
                    accC[i][j] = fmaf(wc4[i], xs[j], accC[i][j]);
        }
        __syncthreads();   // previous chunk's D reads of Ts are done
        {
            const float4 bq = *(const float4*)(bc + rc);
            const float bcv[4] = {bq.x, bq.y, bq.z, bq.w};
#pragma unroll
            for (int i = 0; i < 4; ++i) {
                float4 tv;
                tv.x = fmaxf(accC[i][0] + bcv[i], 0.f);
                tv.y = fmaxf(accC[i][1] + bcv[i], 0.f);
                tv.z = fmaxf(accC[i][2] + bcv[i], 0.f);
                tv.w = fmaxf(accC[i][3] + bcv[i], 0.f);
                *(float4*)&Ts[ty * 4 + i][c0] = tv;
            }
        }
        __syncthreads();
        for (int ic = 0; ic < 64; ++ic) {
            const float4 xv = *(const float4*)&Ts[ic][c0];
            const float4 w0 = *(const float4*)(WdT + (cc * 64 + ic) * 128 + r0);
            const float4 w1 = *(const float4*)(WdT + (cc * 64 + ic) * 128 + r0 + 4);
            const float wd[8] = {w0.x,w0.y,w0.z,w0.w,w1.x,w1.y,w1.z,w1.w};
            const float xs[4] = {xv.x, xv.y, xv.z, xv.w};
#pragma unroll
            for (int i = 0; i < 8; ++i)
#pragma unroll
                for (int j = 0; j < 4; ++j)
                    inv[i][j] = fmaf(wd[i], xs[j], inv[i][j]);
        }
    }

    // ---- out = relu(inv + bd + h); maxpool over K=32 (8 tx-lanes x 4 cols) ----
    {
        const float4 d0 = *(const float4*)(bd + r0);
        const float4 d1 = *(const float4*)(bd + r0 + 4);
        const float bdv[8] = {d0.x,d0.y,d0.z,d0.w,d1.x,d1.y,d1.z,d1.w};
        const int ci   = cen0 + (tx >> 3);
        const int b    = ci >> 10;
        const int mloc = ci & 1023;
#pragma unroll
        for (int i = 0; i < 8; ++i) {
            float o0 = fmaxf((inv[i][0] + bdv[i]) + hreg[i][0], 0.f);
            float o1 = fmaxf((inv[i][1] + bdv[i]) + hreg[i][1], 0.f);
            float o2 = fmaxf((inv[i][2] + bdv[i]) + hreg[i][2], 0.f);
            float o3 = fmaxf((inv[i][3] + bdv[i]) + hreg[i][3], 0.f);
            float v = fmaxf(fmaxf(o0, o1), fmaxf(o2, o3));
            v = fmaxf(v, __shfl_xor(v, 1));
            v = fmaxf(v, __shfl_xor(v, 2));
            v = fmaxf(v, __shfl_xor(v, 4));
            if ((tx & 7) == 0)
                pooled[((size_t)b * 128 + r0 + i) * 1024 + mloc] = v;
        }
    }
}

// ---------------------------------------------------------------------------
extern "C" void kernel_launch(void* const* d_in, const int* in_sizes, int n_in,
                              void* d_out, int out_size, void* d_ws, size_t ws_size,
                              hipStream_t stream)
{
    const float* xyz  = (const float*)d_in[0];
    const float* feat = (const float*)d_in[1];
    const float* Wa = (const float*)d_in[2];   const float* ba = (const float*)d_in[3];
    const float* Wb = (const float*)d_in[4];   const float* bb = (const float*)d_in[5];
    const float* Ws = (const float*)d_in[6];   const float* bs = (const float*)d_in[7];
    const float* Wc = (const float*)d_in[8];   const float* bc = (const float*)d_in[9];
    const float* Wd = (const float*)d_in[10];  const float* bd = (const float*)d_in[11];

    float* out    = (float*)d_out;
    float* newxyz = out;                        // 4*1024*3   = 12288
    float* pooled = out + 4 * 1024 * 3;         // 4*128*1024 = 524288
    float* idxf   = pooled + 4 * 128 * 1024;    // 4*1024     = 4096 (float-encoded ints)

    char* ws = (char*)d_ws;
    int*   nidx = (int*)ws;                         // 4*1024*32 ints = 512 KiB
    float* WaT  = (float*)(ws + 524288);            // 67*128
    float* WbT  = WaT + 67 * 128;                   // 128*128
    float* WsT  = WbT + 128 * 128;                  // 67*128
    float* WcT  = WsT + 67 * 128;                   // 128*512
    float* WdT  = WcT + 128 * 512;                  // 512*128

    transpose_w<<<(128 * 67  + 255) / 256, 256, 0, stream>>>(Wa, WaT, 128, 67);
    transpose_w<<<(128 * 128 + 255) / 256, 256, 0, stream>>>(Wb, WbT, 128, 128);
    transpose_w<<<(128 * 67  + 255) / 256, 256, 0, stream>>>(Ws, WsT, 128, 67);
    transpose_w<<<(512 * 128 + 255) / 256, 256, 0, stream>>>(Wc, WcT, 512, 128);
    transpose_w<<<(128 * 512 + 255) / 256, 256, 0, stream>>>(Wd, WdT, 128, 512);

    fps_kernel<<<4, 1024, 0, stream>>>(xyz, newxyz, idxf);
    ball_kernel<<<1024, 256, 0, stream>>>(xyz, newxyz, nidx);
    mlp_kernel<<<2048, 256, 0, stream>>>(xyz, feat, newxyz, nidx,
                                         WaT, ba, WbT, bb, WsT, bs,
                                         WcT, bc, WdT, bd, pooled);
}

// Round 2
// 2128.524 us; speedup vs baseline: 1.4630x; 1.4630x over previous
//
#include <hip/hip_runtime.h>

#define N_PTS   16384
#define M_CENT  1024
#define K_SMP   32
#define C_FEAT  64
#define C_IN    67
#define NCELL   512

// ---------------------------------------------------------------------------
// 64-bit xor shuffle built from two 32-bit shuffles
__device__ inline unsigned long long shfl_xor_u64(unsigned long long v, int m) {
    int lo = (int)(unsigned int)v;
    int hi = (int)(unsigned int)(v >> 32);
    lo = __shfl_xor(lo, m);
    hi = __shfl_xor(hi, m);
    return ((unsigned long long)(unsigned int)hi << 32) | (unsigned int)lo;
}

// Morton cell id (8x8x8 = 512 cells) for spatial sort
__device__ inline int part3(int v) {
    return (v & 1) | ((v & 2) << 2) | ((v & 4) << 4);
}
__device__ inline int cell_of(float x, float y, float z) {
    int xi = (int)(x * 8.0f); xi = xi < 0 ? 0 : (xi > 7 ? 7 : xi);
    int yi = (int)(y * 8.0f); yi = yi < 0 ? 0 : (yi > 7 ? 7 : yi);
    int zi = (int)(z * 8.0f); zi = zi < 0 ? 0 : (zi > 7 ? 7 : zi);
    return part3(xi) | (part3(yi) << 1) | (part3(zi) << 2);
}

// ---------------------------------------------------------------------------
// Spatial sort pre-passes (per batch): histogram -> exclusive scan -> scatter.
__global__ __launch_bounds__(1024) void hist_kernel(
    const float* __restrict__ xyz, int* __restrict__ ghist)
{
    __shared__ int h[NCELL];
    const int b = blockIdx.x, tid = threadIdx.x;
    if (tid < NCELL) h[tid] = 0;
    __syncthreads();
    const float* P = xyz + (size_t)b * N_PTS * 3;
    for (int i = 0; i < 16; ++i) {
        const int p = tid + (i << 10);
        atomicAdd(&h[cell_of(P[p*3], P[p*3+1], P[p*3+2])], 1);
    }
    __syncthreads();
    if (tid < NCELL) ghist[b * NCELL + tid] = h[tid];
}

__global__ __launch_bounds__(NCELL) void scan_kernel(
    const int* __restrict__ ghist, int* __restrict__ gbase)
{
    __shared__ int h[NCELL];
    const int b = blockIdx.x, t = threadIdx.x;
    h[t] = ghist[b * NCELL + t];
    __syncthreads();
    int s = 0;
    for (int i = 0; i < t; ++i) s += h[i];
    gbase[b * NCELL + t] = s;    // doubles as the scatter atomic counter
}

__global__ __launch_bounds__(1024) void scatter_kernel(
    const float* __restrict__ xyz, int* __restrict__ gbase,
    float4* __restrict__ gsxyz)
{
    const int b = blockIdx.x, tid = threadIdx.x;
    const float* P = xyz + (size_t)b * N_PTS * 3;
    for (int i = 0; i < 16; ++i) {
        const int p = tid + (i << 10);
        float x = P[p*3], y = P[p*3+1], z = P[p*3+2];
        int c = cell_of(x, y, z);
        int pos = atomicAdd(&gbase[b * NCELL + c], 1);
        gsxyz[(size_t)b * N_PTS + pos] = make_float4(x, y, z, __int_as_float(p));
    }
}

// ---------------------------------------------------------------------------
// FPS with bit-exact bbox pruning. One block per batch, 1024 threads,
// 16 spatially-contiguous (Morton-sorted) points per lane.
// Skip rule: fminf(mind,d)==mind exactly when d>=mind, so a conservative
// lower bound (point-to-lane-bbox distance, margin 1.5e-5 >> f32 rounding)
// lets whole waves skip without changing any result bit.
__global__ __launch_bounds__(1024) void fps_kernel(
    const float* __restrict__ xyz,      // original (B,N,3) — for point 0
    const float4* __restrict__ gsxyz,   // sorted (x,y,z, orig-bits)
    float* __restrict__ newxyz_out,     // (B,M,3)
    float* __restrict__ idxf_out)       // (B,M) float-encoded orig idx
{
#pragma clang fp contract(off)
    const int b   = blockIdx.x;
    const int tid = threadIdx.x;
    const float4* S = gsxyz + (size_t)b * N_PTS;

    float px[16], py[16], pz[16], mind[16];
    unsigned int klo[16];
    float lox = 1e30f, hix = -1e30f, loy = 1e30f, hiy = -1e30f, loz = 1e30f, hiz = -1e30f;
#pragma unroll
    for (int i = 0; i < 16; ++i) {
        const float4 v = S[tid * 16 + i];
        px[i] = v.x; py[i] = v.y; pz[i] = v.z;
        const int orig = __float_as_int(v.w);
        // high 14 bits: inverted ORIGINAL idx (numpy first-wins tie-break);
        // low 16 bits: sorted idx (for coord re-fetch)
        klo[i] = ((unsigned)(16383 - orig) << 16) | (unsigned)(tid * 16 + i);
        mind[i] = __int_as_float(0x7f800000);   // +inf
        lox = fminf(lox, v.x); hix = fmaxf(hix, v.x);
        loy = fminf(loy, v.y); hiy = fmaxf(hiy, v.y);
        loz = fminf(loz, v.z); hiz = fmaxf(hiz, v.z);
    }

    __shared__ unsigned long long wslot[M_CENT];
    wslot[tid] = 0ull;                          // 1024 threads cover M_CENT

    const float* P = xyz + (size_t)b * N_PTS * 3;
    float cx = P[0], cy = P[1], cz = P[2];
    if (tid == 0) {
        idxf_out[b * M_CENT] = 0.0f;
        newxyz_out[(b * M_CENT) * 3 + 0] = cx;
        newxyz_out[(b * M_CENT) * 3 + 1] = cy;
        newxyz_out[(b * M_CENT) * 3 + 2] = cz;
    }
    __syncthreads();

    unsigned long long bkey = 0x7f80000000000000ull;  // lane max-mind = +inf
    unsigned long long wkey = 0ull;

    for (int j = 1; j < M_CENT; ++j) {
        // lane-level conservative test vs own bbox
        float tx = fmaxf(fmaxf(lox - cx, cx - hix), 0.0f);
        float ty = fmaxf(fmaxf(loy - cy, cy - hiy), 0.0f);
        float tz = fmaxf(fmaxf(loz - cz, cz - hiz), 0.0f);
        float lb = (tx * tx + ty * ty) + tz * tz;
        float lmax = __uint_as_float((unsigned)(bkey >> 32));
        bool need = (lb * 0.999985f) < lmax;

        if (__any(need)) {
            unsigned long long best = 0ull;
#pragma unroll
            for (int i = 0; i < 16; ++i) {
                float dx = px[i] - cx;
                float dy = py[i] - cy;
                float dz = pz[i] - cz;
                float xx = dx * dx, yy = dy * dy, zz = dz * dz;
                float d  = (xx + yy) + zz;                 // numpy order, no fma
                float mn = fminf(mind[i], d);
                mind[i] = mn;
                unsigned long long cand =
                    ((unsigned long long)__float_as_uint(mn) << 32) | klo[i];
                if (cand > best) best = cand;
            }
            bkey = best;
            unsigned long long w = best;
#pragma unroll
            for (int off = 32; off >= 1; off >>= 1) {
                unsigned long long o = shfl_xor_u64(w, off);
                if (o > w) w = o;
            }
            wkey = w;
        }
        if ((tid & 63) == 0) atomicMax(&wslot[j], wkey);
        __syncthreads();

        const unsigned long long wk = wslot[j];
        const unsigned int kl = (unsigned int)wk;
        const int sorted = (int)(kl & 0xFFFFu);
        const float4 wv = S[sorted];               // broadcast load
        cx = wv.x; cy = wv.y; cz = wv.z;
        if (tid == 0) {
            const int orig = 16383 - (int)(kl >> 16);
            idxf_out[b * M_CENT + j] = (float)orig;
            newxyz_out[(b * M_CENT + j) * 3 + 0] = cx;
            newxyz_out[(b * M_CENT + j) * 3 + 1] = cy;
            newxyz_out[(b * M_CENT + j) * 3 + 2] = cz;
        }
    }
}

// ---------------------------------------------------------------------------
// Ball query: one wave per centroid, ballot-based first-32-in-ball scan.
__global__ __launch_bounds__(256) void ball_kernel(
    const float* __restrict__ xyz,
    const float* __restrict__ newxyz,
    int* __restrict__ nidx)
{
#pragma clang fp contract(off)
    const float R2 = (float)(0.1 * 0.1);
    const int gw   = blockIdx.x * 4 + (threadIdx.x >> 6);
    const int lane = threadIdx.x & 63;
    const int b    = gw >> 10;
    const float* P = xyz + (size_t)b * N_PTS * 3;
    const float cx = newxyz[gw * 3 + 0];
    const float cy = newxyz[gw * 3 + 1];
    const float cz = newxyz[gw * 3 + 2];
    int* out = nidx + gw * K_SMP;

    int cnt = 0, first = -1;
    for (int base = 0; base < N_PTS; base += 64) {
        const int n = base + lane;
        float dx = P[n * 3 + 0] - cx;
        float dy = P[n * 3 + 1] - cy;
        float dz = P[n * 3 + 2] - cz;
        float xx = dx * dx, yy = dy * dy, zz = dz * dz;
        float d2 = (xx + yy) + zz;
        bool inb = d2 < R2;
        unsigned long long mask = __ballot(inb);
        if (mask) {
            if (first < 0) first = base + __ffsll(mask) - 1;
            int before = __popcll(mask & ((1ull << lane) - 1ull));
            int slot = cnt + before;
            if (inb && slot < K_SMP) out[slot] = n;
            cnt += __popcll(mask);
            if (cnt >= K_SMP) break;
        }
    }
    for (int s = cnt + lane; s < K_SMP; s += 64) out[s] = first;
}

// ---------------------------------------------------------------------------
// Weight transpose: W (OC,IC) row-major -> WT (IC,OC) row-major
__global__ void transpose_w(const float* __restrict__ src, float* __restrict__ dst,
                            int OC, int IC)
{
    int i = blockIdx.x * 256 + threadIdx.x;
    if (i < OC * IC) {
        int oc = i / IC, ic = i - oc * IC;
        dst[ic * OC + oc] = src[i];
    }
}

// ---------------------------------------------------------------------------
// Fused gather + 5 conv1x1 layers + residuals + maxpool (unchanged).
__global__ __launch_bounds__(256) void mlp_kernel(
    const float* __restrict__ xyz, const float* __restrict__ feat,
    const float* __restrict__ newxyz, const int* __restrict__ nidx,
    const float* __restrict__ WaT, const float* __restrict__ ba,
    const float* __restrict__ WbT, const float* __restrict__ bb,
    const float* __restrict__ WsT, const float* __restrict__ bs,
    const float* __restrict__ WcT, const float* __restrict__ bc,
    const float* __restrict__ WdT, const float* __restrict__ bd,
    float* __restrict__ pooled)
{
    __shared__ __align__(16) float Xs[C_IN][68];
    __shared__ __align__(16) float Hs[128][68];
    __shared__ __align__(16) float Ts[64][68];

    const int tid  = threadIdx.x;
    const int tx   = tid & 15;
    const int ty   = tid >> 4;
    const int c0   = tx * 4;
    const int r0   = ty * 8;
    const int cen0 = blockIdx.x * 2;

    {
        const int c  = tid & 63;
        const int ci = cen0 + (c >> 5);
        const int b  = ci >> 10;
        const int nn = nidx[ci * K_SMP + (c & 31)];
        const float* P = xyz + (size_t)b * N_PTS * 3;
        const float* F = feat + (size_t)b * C_FEAT * N_PTS;
#pragma unroll 1
        for (int rr = (tid >> 6); rr < C_IN; rr += 4) {
            float v;
            if (rr < 3) v = P[nn * 3 + rr] - newxyz[ci * 3 + rr];
            else        v = F[(rr - 3) * N_PTS + nn];
            Xs[rr][c] = v;
        }
    }
    __syncthreads();

    float accA[8][4], accS[8][4];
#pragma unroll
    for (int i = 0; i < 8; ++i)
#pragma unroll
        for (int j = 0; j < 4; ++j) { accA[i][j] = 0.f; accS[i][j] = 0.f; }

    for (int ic = 0; ic < C_IN; ++ic) {
        const float4 xv = *(const float4*)&Xs[ic][c0];
        const float4 a0 = *(const float4*)(WaT + ic * 128 + r0);
        const float4 a1 = *(const float4*)(WaT + ic * 128 + r0 + 4);
        const float4 s0 = *(const float4*)(WsT + ic * 128 + r0);
        const float4 s1 = *(const float4*)(WsT + ic * 128 + r0 + 4);
        const float wa[8] = {a0.x,a0.y,a0.z,a0.w,a1.x,a1.y,a1.z,a1.w};
        const float ws2[8] = {s0.x,s0.y,s0.z,s0.w,s1.x,s1.y,s1.z,s1.w};
        const float xs[4] = {xv.x, xv.y, xv.z, xv.w};
#pragma unroll
        for (int i = 0; i < 8; ++i)
#pragma unroll
            for (int j = 0; j < 4; ++j) {
                accA[i][j] = fmaf(wa[i],  xs[j], accA[i][j]);
                accS[i][j] = fmaf(ws2[i], xs[j], accS[i][j]);
            }
    }

    {
        const float4 b0 = *(const float4*)(ba + r0);
        const float4 b1 = *(const float4*)(ba + r0 + 4);
        const float bav[8] = {b0.x,b0.y,b0.z,b0.w,b1.x,b1.y,b1.z,b1.w};
#pragma unroll
        for (int i = 0; i < 8; ++i) {
            float4 hv;
            hv.x = fmaxf(accA[i][0] + bav[i], 0.f);
            hv.y = fmaxf(accA[i][1] + bav[i], 0.f);
            hv.z = fmaxf(accA[i][2] + bav[i], 0.f);
            hv.w = fmaxf(accA[i][3] + bav[i], 0.f);
            *(float4*)&Hs[r0 + i][c0] = hv;
        }
    }
    __syncthreads();

    float accB[8][4];
#pragma unroll
    for (int i = 0; i < 8; ++i)
#pragma unroll
        for (int j = 0; j < 4; ++j) accB[i][j] = 0.f;

    for (int ic = 0; ic < 128; ++ic) {
        const float4 xv = *(const float4*)&Hs[ic][c0];
        const float4 w0 = *(const float4*)(WbT + ic * 128 + r0);
        const float4 w1 = *(const float4*)(WbT + ic * 128 + r0 + 4);
        const float wb[8] = {w0.x,w0.y,w0.z,w0.w,w1.x,w1.y,w1.z,w1.w};
        const float xs[4] = {xv.x, xv.y, xv.z, xv.w};
#pragma unroll
        for (int i = 0; i < 8; ++i)
#pragma unroll
            for (int j = 0; j < 4; ++j)
                accB[i][j] = fmaf(wb[i], xs[j], accB[i][j]);
    }

    float hreg[8][4];
    {
        const float4 p0 = *(const float4*)(bb + r0);
        const float4 p1 = *(const float4*)(bb + r0 + 4);
        const float4 q0 = *(const float4*)(bs + r0);
        const float4 q1 = *(const float4*)(bs + r0 + 4);
        const float bbv[8] = {p0.x,p0.y,p0.z,p0.w,p1.x,p1.y,p1.z,p1.w};
        const float bsv[8] = {q0.x,q0.y,q0.z,q0.w,q1.x,q1.y,q1.z,q1.w};
#pragma unroll
        for (int i = 0; i < 8; ++i)
#pragma unroll
            for (int j = 0; j < 4; ++j)
                hreg[i][j] = fmaxf((accB[i][j] + bbv[i]) + (accS[i][j] + bsv[i]), 0.f);
    }
    __syncthreads();
#pragma unroll
    for (int i = 0; i < 8; ++i) {
        float4 hv = {hreg[i][0], hreg[i][1], hreg[i][2], hreg[i][3]};
        *(float4*)&Hs[r0 + i][c0] = hv;
    }
    __syncthreads();

    float inv[8][4];
#pragma unroll
    for (int i = 0; i < 8; ++i)
#pragma unroll
        for (int j = 0; j < 4; ++j) inv[i][j] = 0.f;

    for (int cc = 0; cc < 8; ++cc) {
        float accC[4][4];
#pragma unroll
        for (int i = 0; i < 4; ++i)
#pragma unroll
            for (int j = 0; j < 4; ++j) accC[i][j] = 0.f;

        const int rc = cc * 64 + ty * 4;
        for (int ic = 0; ic < 128; ++ic) {
            const float4 xv = *(const float4*)&Hs[ic][c0];
            const float4 w  = *(const float4*)(WcT + ic * 512 + rc);
            const float wc4[4] = {w.x, w.y, w.z, w.w};
            const float xs[4]  = {xv.x, xv.y, xv.z, xv.w};
#pragma unroll
            for (int i = 0; i < 4; ++i)
#pragma unroll
                for (int j = 0; j < 4; ++j)
                    accC[i][j] = fmaf(wc4[i], xs[j], accC[i][j]);
        }
        __syncthreads();
        {
            const float4 bq = *(const float4*)(bc + rc);
            const float bcv[4] = {bq.x, bq.y, bq.z, bq.w};
#pragma unroll
            for (int i = 0; i < 4; ++i) {
                float4 tv;
                tv.x = fmaxf(accC[i][0] + bcv[i], 0.f);
                tv.y = fmaxf(accC[i][1] + bcv[i], 0.f);
                tv.z = fmaxf(accC[i][2] + bcv[i], 0.f);
                tv.w = fmaxf(accC[i][3] + bcv[i], 0.f);
                *(float4*)&Ts[ty * 4 + i][c0] = tv;
            }
        }
        __syncthreads();
        for (int ic = 0; ic < 64; ++ic) {
            const float4 xv = *(const float4*)&Ts[ic][c0];
            const float4 w0 = *(const float4*)(WdT + (cc * 64 + ic) * 128 + r0);
            const float4 w1 = *(const float4*)(WdT + (cc * 64 + ic) * 128 + r0 + 4);
            const float wd[8] = {w0.x,w0.y,w0.z,w0.w,w1.x,w1.y,w1.z,w1.w};
            const float xs[4] = {xv.x, xv.y, xv.z, xv.w};
#pragma unroll
            for (int i = 0; i < 8; ++i)
#pragma unroll
                for (int j = 0; j < 4; ++j)
                    inv[i][j] = fmaf(wd[i], xs[j], inv[i][j]);
        }
    }

    {
        const float4 d0 = *(const float4*)(bd + r0);
        const float4 d1 = *(const float4*)(bd + r0 + 4);
        const float bdv[8] = {d0.x,d0.y,d0.z,d0.w,d1.x,d1.y,d1.z,d1.w};
        const int ci   = cen0 + (tx >> 3);
        const int b    = ci >> 10;
        const int mloc = ci & 1023;
#pragma unroll
        for (int i = 0; i < 8; ++i) {
            float o0 = fmaxf((inv[i][0] + bdv[i]) + hreg[i][0], 0.f);
            float o1 = fmaxf((inv[i][1] + bdv[i]) + hreg[i][1], 0.f);
            float o2 = fmaxf((inv[i][2] + bdv[i]) + hreg[i][2], 0.f);
            float o3 = fmaxf((inv[i][3] + bdv[i]) + hreg[i][3], 0.f);
            float v = fmaxf(fmaxf(o0, o1), fmaxf(o2, o3));
            v = fmaxf(v, __shfl_xor(v, 1));
            v = fmaxf(v, __shfl_xor(v, 2));
            v = fmaxf(v, __shfl_xor(v, 4));
            if ((tx & 7) == 0)
                pooled[((size_t)b * 128 + r0 + i) * 1024 + mloc] = v;
        }
    }
}

// ---------------------------------------------------------------------------
extern "C" void kernel_launch(void* const* d_in, const int* in_sizes, int n_in,
                              void* d_out, int out_size, void* d_ws, size_t ws_size,
                              hipStream_t stream)
{
    const float* xyz  = (const float*)d_in[0];
    const float* feat = (const float*)d_in[1];
    const float* Wa = (const float*)d_in[2];   const float* ba = (const float*)d_in[3];
    const float* Wb = (const float*)d_in[4];   const float* bb = (const float*)d_in[5];
    const float* Ws = (const float*)d_in[6];   const float* bs = (const float*)d_in[7];
    const float* Wc = (const float*)d_in[8];   const float* bc = (const float*)d_in[9];
    const float* Wd = (const float*)d_in[10];  const float* bd = (const float*)d_in[11];

    float* out    = (float*)d_out;
    float* newxyz = out;                        // 4*1024*3
    float* pooled = out + 4 * 1024 * 3;         // 4*128*1024
    float* idxf   = pooled + 4 * 128 * 1024;    // 4*1024 (float-encoded ints)

    char* ws = (char*)d_ws;
    // region 0 (1 MiB): gsxyz during sort+fps, then reused as nidx by ball/mlp
    float4* gsxyz = (float4*)ws;                        // 4*16384*16 = 1 MiB
    int*    nidx  = (int*)ws;                           // 4*1024*32*4 = 512 KiB (after fps)
    float* WaT  = (float*)(ws + (1 << 20));             // 67*128
    float* WbT  = WaT + 67 * 128;                       // 128*128
    float* WsT  = WbT + 128 * 128;                      // 67*128
    float* WcT  = WsT + 67 * 128;                       // 128*512
    float* WdT  = WcT + 128 * 512;                      // 512*128
    int*   ghist = (int*)(WdT + 512 * 128);             // 4*512
    int*   gbase = ghist + 4 * NCELL;                   // 4*512

    transpose_w<<<(128 * 67  + 255) / 256, 256, 0, stream>>>(Wa, WaT, 128, 67);
    transpose_w<<<(128 * 128 + 255) / 256, 256, 0, stream>>>(Wb, WbT, 128, 128);
    transpose_w<<<(128 * 67  + 255) / 256, 256, 0, stream>>>(Ws, WsT, 128, 67);
    transpose_w<<<(512 * 128 + 255) / 256, 256, 0, stream>>>(Wc, WcT, 512, 128);
    transpose_w<<<(128 * 512 + 255) / 256, 256, 0, stream>>>(Wd, WdT, 128, 512);

    hist_kernel   <<<4, 1024,  0, stream>>>(xyz, ghist);
    scan_kernel   <<<4, NCELL, 0, stream>>>(ghist, gbase);
    scatter_kernel<<<4, 1024,  0, stream>>>(xyz, gbase, gsxyz);

    fps_kernel<<<4, 1024, 0, stream>>>(xyz, gsxyz, newxyz, idxf);
    ball_kernel<<<1024, 256, 0, stream>>>(xyz, newxyz, nidx);
    mlp_kernel<<<2048, 256, 0, stream>>>(xyz, feat, newxyz, nidx,
                                         WaT, ba, WbT, bb, WsT, bs,
                                         WcT, bc, WdT, bd, pooled);
}

// Round 3
// 1606.075 us; speedup vs baseline: 1.9389x; 1.3253x over previous
//
#include <hip/hip_runtime.h>

#define N_PTS   16384
#define M_CENT  1024
#define K_SMP   32
#define C_FEAT  64
#define NCELL   512

using bf16x8 = __attribute__((ext_vector_type(8))) short;
using s16x4  = __attribute__((ext_vector_type(4))) short;
using f32x4  = __attribute__((ext_vector_type(4))) float;

__device__ inline short f2bf(float f) {            // f32 -> bf16 RNE
    unsigned u = __float_as_uint(f);
    u += 0x7fffu + ((u >> 16) & 1u);
    return (short)(u >> 16);
}

// Morton cell id (8x8x8 = 512 cells)
__device__ inline int part3(int v) {
    return (v & 1) | ((v & 2) << 2) | ((v & 4) << 4);
}
__device__ inline int cell_of(float x, float y, float z) {
    int xi = (int)(x * 8.0f); xi = xi < 0 ? 0 : (xi > 7 ? 7 : xi);
    int yi = (int)(y * 8.0f); yi = yi < 0 ? 0 : (yi > 7 ? 7 : yi);
    int zi = (int)(z * 8.0f); zi = zi < 0 ? 0 : (zi > 7 ? 7 : zi);
    return part3(xi) | (part3(yi) << 1) | (part3(zi) << 2);
}

// ---------------------------------------------------------------------------
__global__ __launch_bounds__(1024) void hist_kernel(
    const float* __restrict__ xyz, int* __restrict__ ghist)
{
    __shared__ int h[NCELL];
    const int b = blockIdx.x, tid = threadIdx.x;
    if (tid < NCELL) h[tid] = 0;
    __syncthreads();
    const float* P = xyz + (size_t)b * N_PTS * 3;
    for (int i = 0; i < 16; ++i) {
        const int p = tid + (i << 10);
        atomicAdd(&h[cell_of(P[p*3], P[p*3+1], P[p*3+2])], 1);
    }
    __syncthreads();
    if (tid < NCELL) ghist[b * NCELL + tid] = h[tid];
}

__global__ __launch_bounds__(NCELL) void scan_kernel(
    const int* __restrict__ ghist, int* __restrict__ gbase)
{
    __shared__ int h[NCELL];
    const int b = blockIdx.x, t = threadIdx.x;
    h[t] = ghist[b * NCELL + t];
    __syncthreads();
    int s = 0;
    for (int i = 0; i < t; ++i) s += h[i];
    gbase[b * NCELL + t] = s;
}

__global__ __launch_bounds__(1024) void scatter_kernel(
    const float* __restrict__ xyz, int* __restrict__ gbase,
    float4* __restrict__ gsxyz)
{
    const int b = blockIdx.x, tid = threadIdx.x;
    const float* P = xyz + (size_t)b * N_PTS * 3;
    for (int i = 0; i < 16; ++i) {
        const int p = tid + (i << 10);
        float x = P[p*3], y = P[p*3+1], z = P[p*3+2];
        int c = cell_of(x, y, z);
        int pos = atomicAdd(&gbase[b * NCELL + c], 1);
        gsxyz[(size_t)b * N_PTS + pos] = make_float4(x, y, z, __int_as_float(p));
    }
}

// ---------------------------------------------------------------------------
// FPS, bit-exact pruned. New this round: wave-level bbox pre-test and a
// same-address LDS atomicMax reduce (DS pipe is in-order per wave) replacing
// the 12-op dependent u64 shuffle chain.
__global__ __launch_bounds__(1024) void fps_kernel(
    const float* __restrict__ xyz,
    const float4* __restrict__ gsxyz,
    float* __restrict__ newxyz_out,
    float* __restrict__ idxf_out)
{
#pragma clang fp contract(off)
    const int b = blockIdx.x, tid = threadIdx.x;
    const int wid = tid >> 6, lane = tid & 63;
    const float4* S = gsxyz + (size_t)b * N_PTS;

    float px[16], py[16], pz[16], mind[16];
    unsigned klo[16];
    float lox = 1e30f, hix = -1e30f, loy = 1e30f, hiy = -1e30f, loz = 1e30f, hiz = -1e30f;
#pragma unroll
    for (int i = 0; i < 16; ++i) {
        const float4 v = S[tid * 16 + i];
        px[i] = v.x; py[i] = v.y; pz[i] = v.z;
        const int orig = __float_as_int(v.w);
        klo[i] = ((unsigned)(16383 - orig) << 16) | (unsigned)(tid * 16 + i);
        mind[i] = __int_as_float(0x7f800000);
        lox = fminf(lox, v.x); hix = fmaxf(hix, v.x);
        loy = fminf(loy, v.y); hiy = fmaxf(hiy, v.y);
        loz = fminf(loz, v.z); hiz = fmaxf(hiz, v.z);
    }
    // wave-level bbox (once)
    float wlx = lox, whx = hix, wly = loy, why = hiy, wlz = loz, whz = hiz;
#pragma unroll
    for (int off = 1; off < 64; off <<= 1) {
        wlx = fminf(wlx, __shfl_xor(wlx, off)); whx = fmaxf(whx, __shfl_xor(whx, off));
        wly = fminf(wly, __shfl_xor(wly, off)); why = fmaxf(why, __shfl_xor(why, off));
        wlz = fminf(wlz, __shfl_xor(wlz, off)); whz = fmaxf(whz, __shfl_xor(whz, off));
    }

    __shared__ unsigned long long wslot[M_CENT];
    __shared__ unsigned long long wbest[16];
    wslot[tid] = 0ull;
    if (tid < 16) wbest[tid] = 0ull;

    const float* P = xyz + (size_t)b * N_PTS * 3;
    float cx = P[0], cy = P[1], cz = P[2];
    if (tid == 0) {
        idxf_out[b * M_CENT] = 0.0f;
        newxyz_out[(b * M_CENT) * 3 + 0] = cx;
        newxyz_out[(b * M_CENT) * 3 + 1] = cy;
        newxyz_out[(b * M_CENT) * 3 + 2] = cz;
    }
    __syncthreads();

    unsigned long long bkey = 0x7f80000000000000ull;   // lane max-mind = +inf
    unsigned long long wkey = 0x7f80000000000000ull;   // wave max-mind = +inf

    for (int j = 1; j < M_CENT; ++j) {
        // wave-level conservative reject
        float twx = fmaxf(fmaxf(wlx - cx, cx - whx), 0.0f);
        float twy = fmaxf(fmaxf(wly - cy, cy - why), 0.0f);
        float twz = fmaxf(fmaxf(wlz - cz, cz - whz), 0.0f);
        float wlb = (twx * twx + twy * twy) + twz * twz;
        float wmax = __uint_as_float((unsigned)(wkey >> 32));
        if (wlb * 0.999985f < wmax) {
            float tx = fmaxf(fmaxf(lox - cx, cx - hix), 0.0f);
            float ty = fmaxf(fmaxf(loy - cy, cy - hiy), 0.0f);
            float tz = fmaxf(fmaxf(loz - cz, cz - hiz), 0.0f);
            float lb = (tx * tx + ty * ty) + tz * tz;
            float lmax = __uint_as_float((unsigned)(bkey >> 32));
            bool need = (lb * 0.999985f) < lmax;
            if (__any(need)) {
                unsigned long long best = 0ull;
#pragma unroll
                for (int i = 0; i < 16; ++i) {
                    float dx = px[i] - cx;
                    float dy = py[i] - cy;
                    float dz = pz[i] - cz;
                    float xx = dx * dx, yy = dy * dy, zz = dz * dz;
                    float d  = (xx + yy) + zz;            // numpy order, no fma
                    float mn = fminf(mind[i], d);
                    mind[i] = mn;
                    unsigned long long cand =
                        ((unsigned long long)__float_as_uint(mn) << 32) | klo[i];
                    if (cand > best) best = cand;
                }
                bkey = best;
                atomicMax(&wbest[wid], best);      // 64 lanes, same address
                unsigned long long nw = wbest[wid];// in-order DS pipe: sees all
                wkey = nw;
                if (lane == 0) wbest[wid] = 0ull;  // reset for next use
            }
        }
        if (lane == 0) atomicMax(&wslot[j], wkey);
        __syncthreads();

        const unsigned long long wk = wslot[j];
        const unsigned int kl = (unsigned int)wk;
        const int sorted = (int)(kl & 0xFFFFu);
        const float4 wv = S[sorted];
        cx = wv.x; cy = wv.y; cz = wv.z;
        if (tid == 0) {
            const int orig = 16383 - (int)(kl >> 16);
            idxf_out[b * M_CENT + j] = (float)orig;
            newxyz_out[(b * M_CENT + j) * 3 + 0] = cx;
            newxyz_out[(b * M_CENT + j) * 3 + 1] = cy;
            newxyz_out[(b * M_CENT + j) * 3 + 2] = cz;
        }
    }
}

// ---------------------------------------------------------------------------
__global__ __launch_bounds__(256) void ball_kernel(
    const float* __restrict__ xyz,
    const float* __restrict__ newxyz,
    int* __restrict__ nidx)
{
#pragma clang fp contract(off)
    const float R2 = (float)(0.1 * 0.1);
    const int gw   = blockIdx.x * 4 + (threadIdx.x >> 6);
    const int lane = threadIdx.x & 63;
    const int b    = gw >> 10;
    const float* P = xyz + (size_t)b * N_PTS * 3;
    const float cx = newxyz[gw * 3 + 0];
    const float cy = newxyz[gw * 3 + 1];
    const float cz = newxyz[gw * 3 + 2];
    int* out = nidx + gw * K_SMP;

    int cnt = 0, first = -1;
    for (int base = 0; base < N_PTS; base += 64) {
        const int n = base + lane;
        float dx = P[n * 3 + 0] - cx;
        float dy = P[n * 3 + 1] - cy;
        float dz = P[n * 3 + 2] - cz;
        float xx = dx * dx, yy = dy * dy, zz = dz * dz;
        float d2 = (xx + yy) + zz;
        bool inb = d2 < R2;
        unsigned long long mask = __ballot(inb);
        if (mask) {
            if (first < 0) first = base + __ffsll(mask) - 1;
            int before = __popcll(mask & ((1ull << lane) - 1ull));
            int slot = cnt + before;
            if (inb && slot < K_SMP) out[slot] = n;
            cnt += __popcll(mask);
            if (cnt >= K_SMP) break;
        }
    }
    for (int s = cnt + lane; s < K_SMP; s += 64) out[s] = first;
}

// ---------------------------------------------------------------------------
// Weight prep: f32 (OC,IC) -> bf16 (OC,ICP). remap=1 reorders input channels
// from [xyz(3), feat(64)] to [feat(64), xyz(3), pad] to match Xt layout.
__global__ void prep_w(const float* __restrict__ src, short* __restrict__ dst,
                       int OC, int IC, int ICP, int remap)
{
    int i = blockIdx.x * 256 + threadIdx.x;
    if (i >= OC * ICP) return;
    int oc = i / ICP, ic = i - oc * ICP;
    float v = 0.0f;
    if (remap) {
        if (ic < 64)      v = src[oc * IC + 3 + ic];
        else if (ic < 67) v = src[oc * IC + (ic - 64)];
    } else if (ic < IC)   v = src[oc * IC + ic];
    dst[i] = f2bf(v);
}

// feat (B,64,N) -> featT (B,N,64)
__global__ __launch_bounds__(256) void tfeat_kernel(
    const float* __restrict__ feat, float* __restrict__ featT)
{
    __shared__ float t[64][65];
    const int b = blockIdx.y;
    const int n0 = blockIdx.x * 64;
    for (int it = 0; it < 16; ++it) {
        int idx = it * 256 + threadIdx.x;
        int c = idx >> 6, n = idx & 63;
        t[c][n] = feat[((size_t)b * 64 + c) * N_PTS + n0 + n];
    }
    __syncthreads();
    for (int it = 0; it < 16; ++it) {
        int idx = it * 256 + threadIdx.x;
        int n = idx >> 6, c = idx & 63;
        featT[((size_t)b * N_PTS + n0 + n) * 64 + c] = t[c][n];
    }
}

// ---------------------------------------------------------------------------
// MFMA MLP: 64 cols (2 centroids) per block, 4 waves, bf16 16x16x32 MFMA.
// Activations col-major in LDS; weights bf16 row-major from L2.
// Frag maps (gfx950, m89-verified): A row=l%16, k=(l/16)*8+e; B col=l%16,
// k=(l/16)*8+e; C/D col=l&15, row=(l>>4)*4+reg.
__global__ __launch_bounds__(256, 2) void mlp_kernel(
    const float* __restrict__ xyz, const float* __restrict__ feat,
    const float* __restrict__ featT, int useT,
    const float* __restrict__ newxyz, const int* __restrict__ nidx,
    const short* __restrict__ WaB, const float* __restrict__ ba,
    const short* __restrict__ WbB, const float* __restrict__ bb,
    const short* __restrict__ WsB, const float* __restrict__ bs,
    const short* __restrict__ WcB, const float* __restrict__ bc,
    const short* __restrict__ WdB, const float* __restrict__ bd,
    float* __restrict__ pooled)
{
    __shared__ short Xt[64][104];   // [col][ic0..95], stride 104 (bank-safe)
    __shared__ short Ht[64][136];   // [col][oc0..127], stride 136
    __shared__ short Tt[64][136];

    const int tid = threadIdx.x;
    const int w = tid >> 6, l = tid & 63, l16 = l & 15, kg = l >> 4;
    const int cen0 = blockIdx.x * 2;
    const int b = cen0 >> 10;
    const int ocw = 32 * w;

    // ---- gather: Xt[col] = [feat(64) | rel_xyz(3) | 0-pad(29)] bf16 ----
    {
        const int col = tid >> 2, part = tid & 3;
        const int ci = cen0 + (col >> 5);
        const int nn = nidx[ci * K_SMP + (col & 31)];
        float v[16];
        if (useT) {
            const f32x4* src = (const f32x4*)(featT + ((size_t)b * N_PTS + nn) * 64 + part * 16);
            f32x4 f0 = src[0], f1 = src[1], f2 = src[2], f3 = src[3];
            v[0]=f0[0]; v[1]=f0[1]; v[2]=f0[2]; v[3]=f0[3];
            v[4]=f1[0]; v[5]=f1[1]; v[6]=f1[2]; v[7]=f1[3];
            v[8]=f2[0]; v[9]=f2[1]; v[10]=f2[2]; v[11]=f2[3];
            v[12]=f3[0]; v[13]=f3[1]; v[14]=f3[2]; v[15]=f3[3];
        } else {
            const float* F = feat + (size_t)b * C_FEAT * N_PTS + nn;
#pragma unroll
            for (int q = 0; q < 16; ++q) v[q] = F[(size_t)(part * 16 + q) * N_PTS];
        }
        bf16x8 h0, h1;
#pragma unroll
        for (int q = 0; q < 8; ++q) { h0[q] = f2bf(v[q]); h1[q] = f2bf(v[q + 8]); }
        *(bf16x8*)&Xt[col][part * 16]     = h0;
        *(bf16x8*)&Xt[col][part * 16 + 8] = h1;
        if (part == 0) {
            bf16x8 hx, z;
#pragma unroll
            for (int q = 0; q < 8; ++q) { hx[q] = 0; z[q] = 0; }
            hx[0] = f2bf(xyz[((size_t)b * N_PTS + nn) * 3 + 0] - newxyz[ci * 3 + 0]);
            hx[1] = f2bf(xyz[((size_t)b * N_PTS + nn) * 3 + 1] - newxyz[ci * 3 + 1]);
            hx[2] = f2bf(xyz[((size_t)b * N_PTS + nn) * 3 + 2] - newxyz[ci * 3 + 2]);
            *(bf16x8*)&Xt[col][64] = hx;
            *(bf16x8*)&Xt[col][72] = z;
            *(bf16x8*)&Xt[col][80] = z;
            *(bf16x8*)&Xt[col][88] = z;
        }
    }
    __syncthreads();

    // ---- stage A+S: K=96, h1 = relu(Wa@g+ba) -> Ht; s acc kept in regs ----
    f32x4 accA[2][4], accS[2][4];
#pragma unroll
    for (int o = 0; o < 2; ++o)
#pragma unroll
        for (int ct = 0; ct < 4; ++ct) {
#pragma unroll
            for (int r = 0; r < 4; ++r) { accA[o][ct][r] = 0.f; accS[o][ct][r] = 0.f; }
        }
#pragma unroll
    for (int k = 0; k < 3; ++k) {
        bf16x8 xb[4];
#pragma unroll
        for (int ct = 0; ct < 4; ++ct)
            xb[ct] = *(const bf16x8*)&Xt[ct * 16 + l16][k * 32 + kg * 8];
#pragma unroll
        for (int o = 0; o < 2; ++o) {
            const int row = ocw + o * 16 + l16;
            bf16x8 wa  = *(const bf16x8*)(WaB + row * 96 + k * 32 + kg * 8);
            bf16x8 wsv = *(const bf16x8*)(WsB + row * 96 + k * 32 + kg * 8);
#pragma unroll
            for (int ct = 0; ct < 4; ++ct) {
                accA[o][ct] = __builtin_amdgcn_mfma_f32_16x16x32_bf16(wa,  xb[ct], accA[o][ct], 0, 0, 0);
                accS[o][ct] = __builtin_amdgcn_mfma_f32_16x16x32_bf16(wsv, xb[ct], accS[o][ct], 0, 0, 0);
            }
        }
    }
#pragma unroll
    for (int o = 0; o < 2; ++o) {
        const f32x4 bav = *(const f32x4*)(ba + ocw + o * 16 + kg * 4);
#pragma unroll
        for (int ct = 0; ct < 4; ++ct) {
            s16x4 hv;
#pragma unroll
            for (int r = 0; r < 4; ++r) hv[r] = f2bf(fmaxf(accA[o][ct][r] + bav[r], 0.f));
            *(s16x4*)&Ht[ct * 16 + l16][ocw + o * 16 + kg * 4] = hv;
        }
    }
    __syncthreads();

    // ---- stage B: h = relu(Wb@h1 + bb + s + bs) ----
    f32x4 accB[2][4];
#pragma unroll
    for (int o = 0; o < 2; ++o)
#pragma unroll
        for (int ct = 0; ct < 4; ++ct) {
#pragma unroll
            for (int r = 0; r < 4; ++r) accB[o][ct][r] = 0.f;
        }
#pragma unroll
    for (int k = 0; k < 4; ++k) {
        bf16x8 xb[4];
#pragma unroll
        for (int ct = 0; ct < 4; ++ct)
            xb[ct] = *(const bf16x8*)&Ht[ct * 16 + l16][k * 32 + kg * 8];
#pragma unroll
        for (int o = 0; o < 2; ++o) {
            const int row = ocw + o * 16 + l16;
            bf16x8 wbv = *(const bf16x8*)(WbB + row * 128 + k * 32 + kg * 8);
#pragma unroll
            for (int ct = 0; ct < 4; ++ct)
                accB[o][ct] = __builtin_amdgcn_mfma_f32_16x16x32_bf16(wbv, xb[ct], accB[o][ct], 0, 0, 0);
        }
    }
    f32x4 hreg[2][4];
#pragma unroll
    for (int o = 0; o < 2; ++o) {
        const f32x4 bbv = *(const f32x4*)(bb + ocw + o * 16 + kg * 4);
        const f32x4 bsv = *(const f32x4*)(bs + ocw + o * 16 + kg * 4);
#pragma unroll
        for (int ct = 0; ct < 4; ++ct) {
#pragma unroll
            for (int r = 0; r < 4; ++r)
                hreg[o][ct][r] = fmaxf((accB[o][ct][r] + bbv[r]) + (accS[o][ct][r] + bsv[r]), 0.f);
        }
    }
    __syncthreads();
#pragma unroll
    for (int o = 0; o < 2; ++o)
#pragma unroll
        for (int ct = 0; ct < 4; ++ct) {
            s16x4 hv;
#pragma unroll
            for (int r = 0; r < 4; ++r) hv[r] = f2bf(hreg[o][ct][r]);
            *(s16x4*)&Ht[ct * 16 + l16][ocw + o * 16 + kg * 4] = hv;
        }
    __syncthreads();

    // ---- stages C+D: 4 chunks of 128 Wc rows; D accumulates over chunks ----
    f32x4 accD[2][4];
#pragma unroll
    for (int o = 0; o < 2; ++o)
#pragma unroll
        for (int ct = 0; ct < 4; ++ct) {
#pragma unroll
            for (int r = 0; r < 4; ++r) accD[o][ct][r] = 0.f;
        }
    for (int cc = 0; cc < 4; ++cc) {
        f32x4 accC[2][4];
#pragma unroll
        for (int o = 0; o < 2; ++o)
#pragma unroll
            for (int ct = 0; ct < 4; ++ct) {
#pragma unroll
                for (int r = 0; r < 4; ++r) accC[o][ct][r] = 0.f;
            }
#pragma unroll
        for (int k = 0; k < 4; ++k) {
            bf16x8 xb[4];
#pragma unroll
            for (int ct = 0; ct < 4; ++ct)
                xb[ct] = *(const bf16x8*)&Ht[ct * 16 + l16][k * 32 + kg * 8];
#pragma unroll
            for (int o = 0; o < 2; ++o) {
                const int row = cc * 128 + ocw + o * 16 + l16;
                bf16x8 wcv = *(const bf16x8*)(WcB + row * 128 + k * 32 + kg * 8);
#pragma unroll
                for (int ct = 0; ct < 4; ++ct)
                    accC[o][ct] = __builtin_amdgcn_mfma_f32_16x16x32_bf16(wcv, xb[ct], accC[o][ct], 0, 0, 0);
            }
        }
        __syncthreads();   // prior chunk's Tt reads done
#pragma unroll
        for (int o = 0; o < 2; ++o) {
            const f32x4 bcv = *(const f32x4*)(bc + cc * 128 + ocw + o * 16 + kg * 4);
#pragma unroll
            for (int ct = 0; ct < 4; ++ct) {
                s16x4 tv;
#pragma unroll
                for (int r = 0; r < 4; ++r) tv[r] = f2bf(fmaxf(accC[o][ct][r] + bcv[r], 0.f));
                *(s16x4*)&Tt[ct * 16 + l16][ocw + o * 16 + kg * 4] = tv;
            }
        }
        __syncthreads();
#pragma unroll
        for (int k = 0; k < 4; ++k) {
            bf16x8 tb[4];
#pragma unroll
            for (int ct = 0; ct < 4; ++ct)
                tb[ct] = *(const bf16x8*)&Tt[ct * 16 + l16][k * 32 + kg * 8];
#pragma unroll
            for (int o = 0; o < 2; ++o) {
                const int row = ocw + o * 16 + l16;
                bf16x8 wdv = *(const bf16x8*)(WdB + row * 512 + cc * 128 + k * 32 + kg * 8);
#pragma unroll
                for (int ct = 0; ct < 4; ++ct)
                    accD[o][ct] = __builtin_amdgcn_mfma_f32_16x16x32_bf16(wdv, tb[ct], accD[o][ct], 0, 0, 0);
            }
        }
    }

    // ---- out = relu(accD + bd + h); maxpool over 32 cols per centroid ----
    const int m0 = cen0 & 1023;
#pragma unroll
    for (int o = 0; o < 2; ++o) {
        const f32x4 bdv = *(const f32x4*)(bd + ocw + o * 16 + kg * 4);
#pragma unroll
        for (int r = 0; r < 4; ++r) {
            float a0 = fmaxf((accD[o][0][r] + bdv[r]) + hreg[o][0][r], 0.f);
            float a1 = fmaxf((accD[o][1][r] + bdv[r]) + hreg[o][1][r], 0.f);
            float a2 = fmaxf((accD[o][2][r] + bdv[r]) + hreg[o][2][r], 0.f);
            float a3 = fmaxf((accD[o][3][r] + bdv[r]) + hreg[o][3][r], 0.f);
            float u0 = fmaxf(a0, a1), u1 = fmaxf(a2, a3);
#pragma unroll
            for (int off = 1; off < 16; off <<= 1) {
                u0 = fmaxf(u0, __shfl_xor(u0, off));
                u1 = fmaxf(u1, __shfl_xor(u1, off));
            }
            if (l16 == 0) {
                const int oc = ocw + o * 16 + kg * 4 + r;
                pooled[((size_t)b * 128 + oc) * 1024 + m0]     = u0;
                pooled[((size_t)b * 128 + oc) * 1024 + m0 + 1] = u1;
            }
        }
    }
}

// ---------------------------------------------------------------------------
extern "C" void kernel_launch(void* const* d_in, const int* in_sizes, int n_in,
                              void* d_out, int out_size, void* d_ws, size_t ws_size,
                              hipStream_t stream)
{
    const float* xyz  = (const float*)d_in[0];
    const float* feat = (const float*)d_in[1];
    const float* Wa = (const float*)d_in[2];   const float* ba = (const float*)d_in[3];
    const float* Wb = (const float*)d_in[4];   const float* bb = (const float*)d_in[5];
    const float* Ws = (const float*)d_in[6];   const float* bs = (const float*)d_in[7];
    const float* Wc = (const float*)d_in[8];   const float* bc = (const float*)d_in[9];
    const float* Wd = (const float*)d_in[10];  const float* bd = (const float*)d_in[11];

    float* out    = (float*)d_out;
    float* newxyz = out;
    float* pooled = out + 4 * 1024 * 3;
    float* idxf   = pooled + 4 * 128 * 1024;

    char* ws = (char*)d_ws;
    float4* gsxyz = (float4*)ws;                 // 1 MiB; reused as nidx after fps
    int*    nidx  = (int*)ws;
    short* WaB = (short*)(ws + (1 << 20));       // 128*96
    short* WsB = WaB + 128 * 96;                 // 128*96
    short* WbB = WsB + 128 * 96;                 // 128*128
    short* WcB = WbB + 128 * 128;                // 512*128
    short* WdB = WcB + 512 * 128;                // 128*512
    int*   ghist = (int*)(WdB + 128 * 512);
    int*   gbase = ghist + 4 * NCELL;
    float* featT = (float*)(ws + (2 << 20));     // 16 MiB, optional

    const size_t need = (size_t)(2 << 20) + (size_t)4 * N_PTS * 64 * 4;
    const int useT = (ws_size >= need) ? 1 : 0;

    prep_w<<<(128 *  96 + 255) / 256, 256, 0, stream>>>(Wa, WaB, 128,  67,  96, 1);
    prep_w<<<(128 *  96 + 255) / 256, 256, 0, stream>>>(Ws, WsB, 128,  67,  96, 1);
    prep_w<<<(128 * 128 + 255) / 256, 256, 0, stream>>>(Wb, WbB, 128, 128, 128, 0);
    prep_w<<<(512 * 128 + 255) / 256, 256, 0, stream>>>(Wc, WcB, 512, 128, 128, 0);
    prep_w<<<(128 * 512 + 255) / 256, 256, 0, stream>>>(Wd, WdB, 128, 512, 512, 0);
    if (useT) tfeat_kernel<<<dim3(N_PTS / 64, 4), 256, 0, stream>>>(feat, featT);

    hist_kernel   <<<4, 1024,  0, stream>>>(xyz, ghist);
    scan_kernel   <<<4, NCELL, 0, stream>>>(ghist, gbase);
    scatter_kernel<<<4, 1024,  0, stream>>>(xyz, gbase, gsxyz);

    fps_kernel<<<4, 1024, 0, stream>>>(xyz, gsxyz, newxyz, idxf);
    ball_kernel<<<1024, 256, 0, stream>>>(xyz, newxyz, nidx);
    mlp_kernel<<<2048, 256, 0, stream>>>(xyz, feat, featT, useT, newxyz, nidx,
                                         WaB, ba, WbB, bb, WsB, bs,
                                         WcB, bc, WdB, bd, pooled);
}

// Round 4
// 1590.983 us; speedup vs baseline: 1.9573x; 1.0095x over previous
//
#include <hip/hip_runtime.h>

#define N_PTS   16384
#define M_CENT  1024
#define K_SMP   32
#define C_FEAT  64
#define NCELL   512

using bf16x8 = __attribute__((ext_vector_type(8))) short;
using s16x4  = __attribute__((ext_vector_type(4))) short;
using f32x4  = __attribute__((ext_vector_type(4))) float;

__device__ inline short f2bf(float f) {            // f32 -> bf16 RNE
    unsigned u = __float_as_uint(f);
    u += 0x7fffu + ((u >> 16) & 1u);
    return (short)(u >> 16);
}

// 64-bit xor shuffle from two 32-bit shuffles
__device__ inline unsigned long long shfl_xor_u64(unsigned long long v, int m) {
    int lo = (int)(unsigned int)v;
    int hi = (int)(unsigned int)(v >> 32);
    lo = __shfl_xor(lo, m);
    hi = __shfl_xor(hi, m);
    return ((unsigned long long)(unsigned int)hi << 32) | (unsigned int)lo;
}

// Morton cell id (8x8x8 = 512 cells)
__device__ inline int part3(int v) {
    return (v & 1) | ((v & 2) << 2) | ((v & 4) << 4);
}
__device__ inline int cell_of(float x, float y, float z) {
    int xi = (int)(x * 8.0f); xi = xi < 0 ? 0 : (xi > 7 ? 7 : xi);
    int yi = (int)(y * 8.0f); yi = yi < 0 ? 0 : (yi > 7 ? 7 : yi);
    int zi = (int)(z * 8.0f); zi = zi < 0 ? 0 : (zi > 7 ? 7 : zi);
    return part3(xi) | (part3(yi) << 1) | (part3(zi) << 2);
}

// ---------------------------------------------------------------------------
__global__ __launch_bounds__(1024) void hist_kernel(
    const float* __restrict__ xyz, int* __restrict__ ghist)
{
    __shared__ int h[NCELL];
    const int b = blockIdx.x, tid = threadIdx.x;
    if (tid < NCELL) h[tid] = 0;
    __syncthreads();
    const float* P = xyz + (size_t)b * N_PTS * 3;
    for (int i = 0; i < 16; ++i) {
        const int p = tid + (i << 10);
        atomicAdd(&h[cell_of(P[p*3], P[p*3+1], P[p*3+2])], 1);
    }
    __syncthreads();
    if (tid < NCELL) ghist[b * NCELL + tid] = h[tid];
}

__global__ __launch_bounds__(NCELL) void scan_kernel(
    const int* __restrict__ ghist, int* __restrict__ gbase)
{
    __shared__ int h[NCELL];
    const int b = blockIdx.x, t = threadIdx.x;
    h[t] = ghist[b * NCELL + t];
    __syncthreads();
    int s = 0;
    for (int i = 0; i < t; ++i) s += h[i];
    gbase[b * NCELL + t] = s;
}

__global__ __launch_bounds__(1024) void scatter_kernel(
    const float* __restrict__ xyz, int* __restrict__ gbase,
    float4* __restrict__ gsxyz)
{
    const int b = blockIdx.x, tid = threadIdx.x;
    const float* P = xyz + (size_t)b * N_PTS * 3;
    for (int i = 0; i < 16; ++i) {
        const int p = tid + (i << 10);
        float x = P[p*3], y = P[p*3+1], z = P[p*3+2];
        int c = cell_of(x, y, z);
        int pos = atomicAdd(&gbase[b * NCELL + c], 1);
        gsxyz[(size_t)b * N_PTS + pos] = make_float4(x, y, z, __int_as_float(p));
    }
}

// ---------------------------------------------------------------------------
// FPS, bit-exact pruned. Reduce: intra-wave 6-step u64 shuffle chain (cached
// across iterations when the wave's lane bboxes prove no mind can change),
// then cross-wave via plain parity-double-buffered LDS writes + one barrier
// + 4-step shuffle. NO LDS atomics anywhere.
__global__ __launch_bounds__(1024) void fps_kernel(
    const float* __restrict__ xyz,
    const float4* __restrict__ gsxyz,
    float* __restrict__ newxyz_out,
    float* __restrict__ idxf_out)
{
#pragma clang fp contract(off)
    const int b = blockIdx.x, tid = threadIdx.x;
    const int wid = tid >> 6, lane = tid & 63;
    const float4* S = gsxyz + (size_t)b * N_PTS;

    float px[16], py[16], pz[16], mind[16];
    unsigned klo[16];
    float lox = 1e30f, hix = -1e30f, loy = 1e30f, hiy = -1e30f, loz = 1e30f, hiz = -1e30f;
#pragma unroll
    for (int i = 0; i < 16; ++i) {
        const float4 v = S[tid * 16 + i];
        px[i] = v.x; py[i] = v.y; pz[i] = v.z;
        const int orig = __float_as_int(v.w);
        klo[i] = ((unsigned)(16383 - orig) << 16) | (unsigned)(tid * 16 + i);
        mind[i] = __int_as_float(0x7f800000);
        lox = fminf(lox, v.x); hix = fmaxf(hix, v.x);
        loy = fminf(loy, v.y); hiy = fmaxf(hiy, v.y);
        loz = fminf(loz, v.z); hiz = fmaxf(hiz, v.z);
    }

    __shared__ unsigned long long wblk[2][16];   // parity double-buffer

    const float* P = xyz + (size_t)b * N_PTS * 3;
    float cx = P[0], cy = P[1], cz = P[2];
    if (tid == 0) {
        idxf_out[b * M_CENT] = 0.0f;
        newxyz_out[(b * M_CENT) * 3 + 0] = cx;
        newxyz_out[(b * M_CENT) * 3 + 1] = cy;
        newxyz_out[(b * M_CENT) * 3 + 2] = cz;
    }
    __syncthreads();

    unsigned long long bkey = 0x7f80000000000000ull;   // lane max-mind = +inf
    unsigned long long wkey = 0x7f80000000000000ull;   // wave max-mind = +inf

    for (int j = 1; j < M_CENT; ++j) {
        const int par = j & 1;
        // lane-level conservative reject (skip is bit-exact: fminf(mind,d)==mind
        // whenever d>=mind; margin 1.5e-5 >> worst-case f32 rounding of bound)
        float tx = fmaxf(fmaxf(lox - cx, cx - hix), 0.0f);
        float ty = fmaxf(fmaxf(loy - cy, cy - hiy), 0.0f);
        float tz = fmaxf(fmaxf(loz - cz, cz - hiz), 0.0f);
        float lb = (tx * tx + ty * ty) + tz * tz;
        float lmax = __uint_as_float((unsigned)(bkey >> 32));
        bool need = (lb * 0.999985f) < lmax;

        if (__any(need)) {
            // pass 1: distances + value-only max
            float bv = -1.0f;
#pragma unroll
            for (int i = 0; i < 16; ++i) {
                float dx = px[i] - cx;
                float dy = py[i] - cy;
                float dz = pz[i] - cz;
                float xx = dx * dx, yy = dy * dy, zz = dz * dz;
                float d  = (xx + yy) + zz;            // numpy order, no fma
                float mn = fminf(mind[i], d);
                mind[i] = mn;
                bv = fmaxf(bv, mn);
            }
            // pass 2: tie-break (max klo = smallest original idx)
            unsigned bk = 0u;
#pragma unroll
            for (int i = 0; i < 16; ++i)
                if (mind[i] == bv && klo[i] > bk) bk = klo[i];
            bkey = ((unsigned long long)__float_as_uint(bv) << 32) | bk;

            unsigned long long w = bkey;
#pragma unroll
            for (int off = 32; off >= 1; off >>= 1) {
                unsigned long long o = shfl_xor_u64(w, off);
                if (o > w) w = o;
            }
            wkey = w;
        }
        if (lane == 0) wblk[par][wid] = wkey;
        __syncthreads();

        unsigned long long k2 = wblk[par][lane & 15];
#pragma unroll
        for (int off = 8; off >= 1; off >>= 1) {
            unsigned long long o = shfl_xor_u64(k2, off);
            if (o > k2) k2 = o;
        }
        const unsigned int kl = (unsigned int)k2;
        const int sorted = (int)(kl & 0xFFFFu);
        const float4 wv = S[sorted];               // broadcast L2 read
        cx = wv.x; cy = wv.y; cz = wv.z;
        if (tid == 0) {
            const int orig = 16383 - (int)(kl >> 16);
            idxf_out[b * M_CENT + j] = (float)orig;
            newxyz_out[(b * M_CENT + j) * 3 + 0] = cx;
            newxyz_out[(b * M_CENT + j) * 3 + 1] = cy;
            newxyz_out[(b * M_CENT + j) * 3 + 2] = cz;
        }
        // no second barrier: next iter writes parity ^1, and a wave cannot
        // reach parity `par` again without passing the next barrier, which
        // happens-after every wave's read above.
    }
}

// ---------------------------------------------------------------------------
__global__ __launch_bounds__(256) void ball_kernel(
    const float* __restrict__ xyz,
    const float* __restrict__ newxyz,
    int* __restrict__ nidx)
{
#pragma clang fp contract(off)
    const float R2 = (float)(0.1 * 0.1);
    const int gw   = blockIdx.x * 4 + (threadIdx.x >> 6);
    const int lane = threadIdx.x & 63;
    const int b    = gw >> 10;
    const float* P = xyz + (size_t)b * N_PTS * 3;
    const float cx = newxyz[gw * 3 + 0];
    const float cy = newxyz[gw * 3 + 1];
    const float cz = newxyz[gw * 3 + 2];
    int* out = nidx + gw * K_SMP;

    int cnt = 0, first = -1;
    for (int base = 0; base < N_PTS; base += 64) {
        const int n = base + lane;
        float dx = P[n * 3 + 0] - cx;
        float dy = P[n * 3 + 1] - cy;
        float dz = P[n * 3 + 2] - cz;
        float xx = dx * dx, yy = dy * dy, zz = dz * dz;
        float d2 = (xx + yy) + zz;
        bool inb = d2 < R2;
        unsigned long long mask = __ballot(inb);
        if (mask) {
            if (first < 0) first = base + __ffsll(mask) - 1;
            int before = __popcll(mask & ((1ull << lane) - 1ull));
            int slot = cnt + before;
            if (inb && slot < K_SMP) out[slot] = n;
            cnt += __popcll(mask);
            if (cnt >= K_SMP) break;
        }
    }
    for (int s = cnt + lane; s < K_SMP; s += 64) out[s] = first;
}

// ---------------------------------------------------------------------------
// Weight prep: f32 (OC,IC) -> bf16 (OC,ICP). remap=1 reorders input channels
// from [xyz(3), feat(64)] to [feat(64), xyz(3), pad] to match Xt layout.
__global__ void prep_w(const float* __restrict__ src, short* __restrict__ dst,
                       int OC, int IC, int ICP, int remap)
{
    int i = blockIdx.x * 256 + threadIdx.x;
    if (i >= OC * ICP) return;
    int oc = i / ICP, ic = i - oc * ICP;
    float v = 0.0f;
    if (remap) {
        if (ic < 64)      v = src[oc * IC + 3 + ic];
        else if (ic < 67) v = src[oc * IC + (ic - 64)];
    } else if (ic < IC)   v = src[oc * IC + ic];
    dst[i] = f2bf(v);
}

// feat (B,64,N) -> featT (B,N,64)
__global__ __launch_bounds__(256) void tfeat_kernel(
    const float* __restrict__ feat, float* __restrict__ featT)
{
    __shared__ float t[64][65];
    const int b = blockIdx.y;
    const int n0 = blockIdx.x * 64;
    for (int it = 0; it < 16; ++it) {
        int idx = it * 256 + threadIdx.x;
        int c = idx >> 6, n = idx & 63;
        t[c][n] = feat[((size_t)b * 64 + c) * N_PTS + n0 + n];
    }
    __syncthreads();
    for (int it = 0; it < 16; ++it) {
        int idx = it * 256 + threadIdx.x;
        int n = idx >> 6, c = idx & 63;
        featT[((size_t)b * N_PTS + n0 + n) * 64 + c] = t[c][n];
    }
}

// ---------------------------------------------------------------------------
// MFMA MLP: 64 cols (2 centroids) per block, 4 waves, bf16 16x16x32 MFMA.
__global__ __launch_bounds__(256, 2) void mlp_kernel(
    const float* __restrict__ xyz, const float* __restrict__ feat,
    const float* __restrict__ featT, int useT,
    const float* __restrict__ newxyz, const int* __restrict__ nidx,
    const short* __restrict__ WaB, const float* __restrict__ ba,
    const short* __restrict__ WbB, const float* __restrict__ bb,
    const short* __restrict__ WsB, const float* __restrict__ bs,
    const short* __restrict__ WcB, const float* __restrict__ bc,
    const short* __restrict__ WdB, const float* __restrict__ bd,
    float* __restrict__ pooled)
{
    __shared__ short Xt[64][104];
    __shared__ short Ht[64][136];
    __shared__ short Tt[64][136];

    const int tid = threadIdx.x;
    const int w = tid >> 6, l = tid & 63, l16 = l & 15, kg = l >> 4;
    const int cen0 = blockIdx.x * 2;
    const int b = cen0 >> 10;
    const int ocw = 32 * w;

    {
        const int col = tid >> 2, part = tid & 3;
        const int ci = cen0 + (col >> 5);
        const int nn = nidx[ci * K_SMP + (col & 31)];
        float v[16];
        if (useT) {
            const f32x4* src = (const f32x4*)(featT + ((size_t)b * N_PTS + nn) * 64 + part * 16);
            f32x4 f0 = src[0], f1 = src[1], f2 = src[2], f3 = src[3];
            v[0]=f0[0]; v[1]=f0[1]; v[2]=f0[2]; v[3]=f0[3];
            v[4]=f1[0]; v[5]=f1[1]; v[6]=f1[2]; v[7]=f1[3];
            v[8]=f2[0]; v[9]=f2[1]; v[10]=f2[2]; v[11]=f2[3];
            v[12]=f3[0]; v[13]=f3[1]; v[14]=f3[2]; v[15]=f3[3];
        } else {
            const float* F = feat + (size_t)b * C_FEAT * N_PTS + nn;
#pragma unroll
            for (int q = 0; q < 16; ++q) v[q] = F[(size_t)(part * 16 + q) * N_PTS];
        }
        bf16x8 h0, h1;
#pragma unroll
        for (int q = 0; q < 8; ++q) { h0[q] = f2bf(v[q]); h1[q] = f2bf(v[q + 8]); }
        *(bf16x8*)&Xt[col][part * 16]     = h0;
        *(bf16x8*)&Xt[col][part * 16 + 8] = h1;
        if (part == 0) {
            bf16x8 hx, z;
#pragma unroll
            for (int q = 0; q < 8; ++q) { hx[q] = 0; z[q] = 0; }
            hx[0] = f2bf(xyz[((size_t)b * N_PTS + nn) * 3 + 0] - newxyz[ci * 3 + 0]);
            hx[1] = f2bf(xyz[((size_t)b * N_PTS + nn) * 3 + 1] - newxyz[ci * 3 + 1]);
            hx[2] = f2bf(xyz[((size_t)b * N_PTS + nn) * 3 + 2] - newxyz[ci * 3 + 2]);
            *(bf16x8*)&Xt[col][64] = hx;
            *(bf16x8*)&Xt[col][72] = z;
            *(bf16x8*)&Xt[col][80] = z;
            *(bf16x8*)&Xt[col][88] = z;
        }
    }
    __syncthreads();

    f32x4 accA[2][4], accS[2][4];
#pragma unroll
    for (int o = 0; o < 2; ++o)
#pragma unroll
        for (int ct = 0; ct < 4; ++ct) {
#pragma unroll
            for (int r = 0; r < 4; ++r) { accA[o][ct][r] = 0.f; accS[o][ct][r] = 0.f; }
        }
#pragma unroll
    for (int k = 0; k < 3; ++k) {
        bf16x8 xb[4];
#pragma unroll
        for (int ct = 0; ct < 4; ++ct)
            xb[ct] = *(const bf16x8*)&Xt[ct * 16 + l16][k * 32 + kg * 8];
#pragma unroll
        for (int o = 0; o < 2; ++o) {
            const int row = ocw + o * 16 + l16;
            bf16x8 wa  = *(const bf16x8*)(WaB + row * 96 + k * 32 + kg * 8);
            bf16x8 wsv = *(const bf16x8*)(WsB + row * 96 + k * 32 + kg * 8);
#pragma unroll
            for (int ct = 0; ct < 4; ++ct) {
                accA[o][ct] = __builtin_amdgcn_mfma_f32_16x16x32_bf16(wa,  xb[ct], accA[o][ct], 0, 0, 0);
                accS[o][ct] = __builtin_amdgcn_mfma_f32_16x16x32_bf16(wsv, xb[ct], accS[o][ct], 0, 0, 0);
            }
        }
    }
#pragma unroll
    for (int o = 0; o < 2; ++o) {
        const f32x4 bav = *(const f32x4*)(ba + ocw + o * 16 + kg * 4);
#pragma unroll
        for (int ct = 0; ct < 4; ++ct) {
            s16x4 hv;
#pragma unroll
            for (int r = 0; r < 4; ++r) hv[r] = f2bf(fmaxf(accA[o][ct][r] + bav[r], 0.f));
            *(s16x4*)&Ht[ct * 16 + l16][ocw + o * 16 + kg * 4] = hv;
        }
    }
    __syncthreads();

    f32x4 accB[2][4];
#pragma unroll
    for (int o = 0; o < 2; ++o)
#pragma unroll
        for (int ct = 0; ct < 4; ++ct) {
#pragma unroll
            for (int r = 0; r < 4; ++r) accB[o][ct][r] = 0.f;
        }
#pragma unroll
    for (int k = 0; k < 4; ++k) {
        bf16x8 xb[4];
#pragma unroll
        for (int ct = 0; ct < 4; ++ct)
            xb[ct] = *(const bf16x8*)&Ht[ct * 16 + l16][k * 32 + kg * 8];
#pragma unroll
        for (int o = 0; o < 2; ++o) {
            const int row = ocw + o * 16 + l16;
            bf16x8 wbv = *(const bf16x8*)(WbB + row * 128 + k * 32 + kg * 8);
#pragma unroll
            for (int ct = 0; ct < 4; ++ct)
                accB[o][ct] = __builtin_amdgcn_mfma_f32_16x16x32_bf16(wbv, xb[ct], accB[o][ct], 0, 0, 0);
        }
    }
    f32x4 hreg[2][4];
#pragma unroll
    for (int o = 0; o < 2; ++o) {
        const f32x4 bbv = *(const f32x4*)(bb + ocw + o * 16 + kg * 4);
        const f32x4 bsv = *(const f32x4*)(bs + ocw + o * 16 + kg * 4);
#pragma unroll
        for (int ct = 0; ct < 4; ++ct) {
#pragma unroll
            for (int r = 0; r < 4; ++r)
                hreg[o][ct][r] = fmaxf((accB[o][ct][r] + bbv[r]) + (accS[o][ct][r] + bsv[r]), 0.f);
        }
    }
    __syncthreads();
#pragma unroll
    for (int o = 0; o < 2; ++o)
#pragma unroll
        for (int ct = 0; ct < 4; ++ct) {
            s16x4 hv;
#pragma unroll
            for (int r = 0; r < 4; ++r) hv[r] = f2bf(hreg[o][ct][r]);
            *(s16x4*)&Ht[ct * 16 + l16][ocw + o * 16 + kg * 4] = hv;
        }
    __syncthreads();

    f32x4 accD[2][4];
#pragma unroll
    for (int o = 0; o < 2; ++o)
#pragma unroll
        for (int ct = 0; ct < 4; ++ct) {
#pragma unroll
            for (int r = 0; r < 4; ++r) accD[o][ct][r] = 0.f;
        }
    for (int cc = 0; cc < 4; ++cc) {
        f32x4 accC[2][4];
#pragma unroll
        for (int o = 0; o < 2; ++o)
#pragma unroll
            for (int ct = 0; ct < 4; ++ct) {
#pragma unroll
                for (int r = 0; r < 4; ++r) accC[o][ct][r] = 0.f;
            }
#pragma unroll
        for (int k = 0; k < 4; ++k) {
            bf16x8 xb[4];
#pragma unroll
            for (int ct = 0; ct < 4; ++ct)
                xb[ct] = *(const bf16x8*)&Ht[ct * 16 + l16][k * 32 + kg * 8];
#pragma unroll
            for (int o = 0; o < 2; ++o) {
                const int row = cc * 128 + ocw + o * 16 + l16;
                bf16x8 wcv = *(const bf16x8*)(WcB + row * 128 + k * 32 + kg * 8);
#pragma unroll
                for (int ct = 0; ct < 4; ++ct)
                    accC[o][ct] = __builtin_amdgcn_mfma_f32_16x16x32_bf16(wcv, xb[ct], accC[o][ct], 0, 0, 0);
            }
        }
        __syncthreads();
#pragma unroll
        for (int o = 0; o < 2; ++o) {
            const f32x4 bcv = *(const f32x4*)(bc + cc * 128 + ocw + o * 16 + kg * 4);
#pragma unroll
            for (int ct = 0; ct < 4; ++ct) {
                s16x4 tv;
#pragma unroll
                for (int r = 0; r < 4; ++r) tv[r] = f2bf(fmaxf(accC[o][ct][r] + bcv[r], 0.f));
                *(s16x4*)&Tt[ct * 16 + l16][ocw + o * 16 + kg * 4] = tv;
            }
        }
        __syncthreads();
#pragma unroll
        for (int k = 0; k < 4; ++k) {
            bf16x8 tb[4];
#pragma unroll
            for (int ct = 0; ct < 4; ++ct)
                tb[ct] = *(const bf16x8*)&Tt[ct * 16 + l16][k * 32 + kg * 8];
#pragma unroll
            for (int o = 0; o < 2; ++o) {
                const int row = ocw + o * 16 + l16;
                bf16x8 wdv = *(const bf16x8*)(WdB + row * 512 + cc * 128 + k * 32 + kg * 8);
#pragma unroll
                for (int ct = 0; ct < 4; ++ct)
                    accD[o][ct] = __builtin_amdgcn_mfma_f32_16x16x32_bf16(wdv, tb[ct], accD[o][ct], 0, 0, 0);
            }
        }
    }

    const int m0 = cen0 & 1023;
#pragma unroll
    for (int o = 0; o < 2; ++o) {
        const f32x4 bdv = *(const f32x4*)(bd + ocw + o * 16 + kg * 4);
#pragma unroll
        for (int r = 0; r < 4; ++r) {
            float a0 = fmaxf((accD[o][0][r] + bdv[r]) + hreg[o][0][r], 0.f);
            float a1 = fmaxf((accD[o][1][r] + bdv[r]) + hreg[o][1][r], 0.f);
            float a2 = fmaxf((accD[o][2][r] + bdv[r]) + hreg[o][2][r], 0.f);
            float a3 = fmaxf((accD[o][3][r] + bdv[r]) + hreg[o][3][r], 0.f);
            float u0 = fmaxf(a0, a1), u1 = fmaxf(a2, a3);
#pragma unroll
            for (int off = 1; off < 16; off <<= 1) {
                u0 = fmaxf(u0, __shfl_xor(u0, off));
                u1 = fmaxf(u1, __shfl_xor(u1, off));
            }
            if (l16 == 0) {
                const int oc = ocw + o * 16 + kg * 4 + r;
                pooled[((size_t)b * 128 + oc) * 1024 + m0]     = u0;
                pooled[((size_t)b * 128 + oc) * 1024 + m0 + 1] = u1;
            }
        }
    }
}

// ---------------------------------------------------------------------------
extern "C" void kernel_launch(void* const* d_in, const int* in_sizes, int n_in,
                              void* d_out, int out_size, void* d_ws, size_t ws_size,
                              hipStream_t stream)
{
    const float* xyz  = (const float*)d_in[0];
    const float* feat = (const float*)d_in[1];
    const float* Wa = (const float*)d_in[2];   const float* ba = (const float*)d_in[3];
    const float* Wb = (const float*)d_in[4];   const float* bb = (const float*)d_in[5];
    const float* Ws = (const float*)d_in[6];   const float* bs = (const float*)d_in[7];
    const float* Wc = (const float*)d_in[8];   const float* bc = (const float*)d_in[9];
    const float* Wd = (const float*)d_in[10];  const float* bd = (const float*)d_in[11];

    float* out    = (float*)d_out;
    float* newxyz = out;
    float* pooled = out + 4 * 1024 * 3;
    float* idxf   = pooled + 4 * 128 * 1024;

    char* ws = (char*)d_ws;
    float4* gsxyz = (float4*)ws;                 // 1 MiB; reused as nidx after fps
    int*    nidx  = (int*)ws;
    short* WaB = (short*)(ws + (1 << 20));       // 128*96
    short* WsB = WaB + 128 * 96;                 // 128*96
    short* WbB = WsB + 128 * 96;                 // 128*128
    short* WcB = WbB + 128 * 128;                // 512*128
    short* WdB = WcB + 512 * 128;                // 128*512
    int*   ghist = (int*)(WdB + 128 * 512);
    int*   gbase = ghist + 4 * NCELL;
    float* featT = (float*)(ws + (2 << 20));     // 16 MiB, optional

    const size_t need = (size_t)(2 << 20) + (size_t)4 * N_PTS * 64 * 4;
    const int useT = (ws_size >= need) ? 1 : 0;

    prep_w<<<(128 *  96 + 255) / 256, 256, 0, stream>>>(Wa, WaB, 128,  67,  96, 1);
    prep_w<<<(128 *  96 + 255) / 256, 256, 0, stream>>>(Ws, WsB, 128,  67,  96, 1);
    prep_w<<<(128 * 128 + 255) / 256, 256, 0, stream>>>(Wb, WbB, 128, 128, 128, 0);
    prep_w<<<(512 * 128 + 255) / 256, 256, 0, stream>>>(Wc, WcB, 512, 128, 128, 0);
    prep_w<<<(128 * 512 + 255) / 256, 256, 0, stream>>>(Wd, WdB, 128, 512, 512, 0);
    if (useT) tfeat_kernel<<<dim3(N_PTS / 64, 4), 256, 0, stream>>>(feat, featT);

    hist_kernel   <<<4, 1024,  0, stream>>>(xyz, ghist);
    scan_kernel   <<<4, NCELL, 0, stream>>>(ghist, gbase);
    scatter_kernel<<<4, 1024,  0, stream>>>(xyz, gbase, gsxyz);

    fps_kernel<<<4, 1024, 0, stream>>>(xyz, gsxyz, newxyz, idxf);
    ball_kernel<<<1024, 256, 0, stream>>>(xyz, newxyz, nidx);
    mlp_kernel<<<2048, 256, 0, stream>>>(xyz, feat, featT, useT, newxyz, nidx,
                                         WaB, ba, WbB, bb, WsB, bs,
                                         WcB, bc, WdB, bd, pooled);
}